// Round 1
// baseline (1927.220 us; speedup 1.0000x reference)
//
#include <hip/hip_runtime.h>
#include <math.h>

#define B_  8
#define T_  400
#define F_  256
#define D_  64
#define K_  16
#define N_  (T_*F_)        // 102400
#define TILE 512
#define NBLK (N_/TILE)     // 200
#define PSTRIDE 20         // post_lds row stride (16 + 4 pad, keeps float4 alignment)

// ---------------- workspace layout (floats) ----------------
// 0      means_s 8192
// 8192   var_s   8192
// 16384  pi_s    128
// 16512  pinv    8192
// 24704  pw      8192
// 32896  pc0     128
// 33024  cs      128     \
// 33152  sx      8192     > contiguous, zeroed per iteration
// 41344  sx2     8192    /

__global__ void initk(const float* __restrict__ means_in,
                      float* __restrict__ means_s, float* __restrict__ var_s,
                      float* __restrict__ pi_s) {
    int i = blockIdx.x * 256 + threadIdx.x;
    if (i < B_*K_*D_) { means_s[i] = means_in[i]; var_s[i] = 1.0f; }
    if (i < B_*K_)    pi_s[i] = 1.0f / K_;
}

// one wave per (b,k): derived params
__global__ void prepk(const float* __restrict__ means_s, const float* __restrict__ var_s,
                      const float* __restrict__ pi_s,
                      float* __restrict__ pinv, float* __restrict__ pw,
                      float* __restrict__ pc0) {
    int bk = blockIdx.x;          // 0..127
    int d  = threadIdx.x;         // 0..63
    int idx = bk * D_ + d;
    float var = var_s[idx];
    float m   = means_s[idx];
    float inv = 1.0f / (var + 1e-6f);
    pinv[idx] = inv;
    pw[idx]   = m * inv;
    float r1 = logf(6.283185307179586f * var);   // log(2*pi*var)
    float r2 = m * m * inv;
    #pragma unroll
    for (int off = 32; off > 0; off >>= 1) {
        r1 += __shfl_xor(r1, off);
        r2 += __shfl_xor(r2, off);
    }
    if (d == 0) pc0[bk] = logf(pi_s[bk]) - 0.5f * (r1 + r2);
}

// fused E-step: lik -> softmax -> block-local reduce -> global atomics
__global__ __launch_bounds__(256, 3) void estepk(
        const float* __restrict__ xg,
        const float* __restrict__ pinv, const float* __restrict__ pw,
        const float* __restrict__ pc0,
        float* __restrict__ cs, float* __restrict__ sx, float* __restrict__ sx2) {
    __shared__ float pinv_lds[K_*D_];
    __shared__ float pw_lds[K_*D_];
    __shared__ float c0_lds[K_];
    __shared__ float post_lds[TILE * PSTRIDE];

    const int t  = threadIdx.x;
    const int b  = blockIdx.y;
    const int n0 = blockIdx.x * TILE;

    for (int i = t; i < K_*D_; i += 256) {
        pinv_lds[i] = pinv[b*K_*D_ + i];
        pw_lds[i]   = pw[b*K_*D_ + i];
    }
    if (t < K_) c0_lds[t] = pc0[b*K_ + t];
    __syncthreads();

    // ---- phase A: two points per thread ----
    float t1a[16], t2a[16], t1b[16], t2b[16];
    #pragma unroll
    for (int k = 0; k < 16; ++k) { t1a[k]=0.f; t2a[k]=0.f; t1b[k]=0.f; t2b[k]=0.f; }

    const float4* pa = (const float4*)(xg + ((size_t)b*N_ + n0 + t) * D_);
    const float4* pb = pa + 256 * (D_/4);
    const float4* iv4 = (const float4*)pinv_lds;
    const float4* wv4 = (const float4*)pw_lds;

    #pragma unroll 2
    for (int c = 0; c < D_/4; ++c) {
        float4 xa = pa[c], xb = pb[c];
        float4 qa, qb;
        qa.x = xa.x*xa.x; qa.y = xa.y*xa.y; qa.z = xa.z*xa.z; qa.w = xa.w*xa.w;
        qb.x = xb.x*xb.x; qb.y = xb.y*xb.y; qb.z = xb.z*xb.z; qb.w = xb.w*xb.w;
        #pragma unroll
        for (int k = 0; k < 16; ++k) {
            float4 iv = iv4[k*16 + c];
            float4 wv = wv4[k*16 + c];
            t2a[k] = fmaf(qa.x, iv.x, fmaf(qa.y, iv.y, fmaf(qa.z, iv.z, fmaf(qa.w, iv.w, t2a[k]))));
            t1a[k] = fmaf(xa.x, wv.x, fmaf(xa.y, wv.y, fmaf(xa.z, wv.z, fmaf(xa.w, wv.w, t1a[k]))));
            t2b[k] = fmaf(qb.x, iv.x, fmaf(qb.y, iv.y, fmaf(qb.z, iv.z, fmaf(qb.w, iv.w, t2b[k]))));
            t1b[k] = fmaf(xb.x, wv.x, fmaf(xb.y, wv.y, fmaf(xb.z, wv.z, fmaf(xb.w, wv.w, t1b[k]))));
        }
    }

    // softmax over K=16 in-thread, post -> LDS
    {
        float lik[16]; float mx = -1e30f;
        #pragma unroll
        for (int k = 0; k < 16; ++k) { lik[k] = c0_lds[k] + t1a[k] - 0.5f*t2a[k]; mx = fmaxf(mx, lik[k]); }
        float s = 0.f;
        #pragma unroll
        for (int k = 0; k < 16; ++k) { lik[k] = __expf(lik[k] - mx); s += lik[k]; }
        float is = 1.0f / s;
        #pragma unroll
        for (int k = 0; k < 16; ++k) post_lds[t*PSTRIDE + k] = lik[k] * is;
    }
    {
        float lik[16]; float mx = -1e30f;
        #pragma unroll
        for (int k = 0; k < 16; ++k) { lik[k] = c0_lds[k] + t1b[k] - 0.5f*t2b[k]; mx = fmaxf(mx, lik[k]); }
        float s = 0.f;
        #pragma unroll
        for (int k = 0; k < 16; ++k) { lik[k] = __expf(lik[k] - mx); s += lik[k]; }
        float is = 1.0f / s;
        #pragma unroll
        for (int k = 0; k < 16; ++k) post_lds[(256 + t)*PSTRIDE + k] = lik[k] * is;
    }
    __syncthreads();

    // ---- phase B: wave w handles k in [4w,4w+4), lane = d ----
    const int lane = t & 63;
    const int kb   = (t >> 6) * 4;
    float sa[4]  = {0.f,0.f,0.f,0.f};
    float s2a[4] = {0.f,0.f,0.f,0.f};
    float ca[4]  = {0.f,0.f,0.f,0.f};
    const float* xrow = xg + ((size_t)b*N_ + n0) * D_ + lane;
    #pragma unroll 4
    for (int n = 0; n < TILE; ++n) {
        float xv = xrow[(size_t)n * D_];
        float4 p = *(const float4*)&post_lds[n*PSTRIDE + kb];
        float xx = xv * xv;
        ca[0] += p.x; ca[1] += p.y; ca[2] += p.z; ca[3] += p.w;
        sa[0] = fmaf(p.x, xv, sa[0]);  sa[1] = fmaf(p.y, xv, sa[1]);
        sa[2] = fmaf(p.z, xv, sa[2]);  sa[3] = fmaf(p.w, xv, sa[3]);
        s2a[0] = fmaf(p.x, xx, s2a[0]); s2a[1] = fmaf(p.y, xx, s2a[1]);
        s2a[2] = fmaf(p.z, xx, s2a[2]); s2a[3] = fmaf(p.w, xx, s2a[3]);
    }
    #pragma unroll
    for (int i = 0; i < 4; ++i) {
        atomicAdd(&sx [((size_t)b*K_ + kb + i)*D_ + lane], sa[i]);
        atomicAdd(&sx2[((size_t)b*K_ + kb + i)*D_ + lane], s2a[i]);
    }
    if (lane == 0) {
        #pragma unroll
        for (int i = 0; i < 4; ++i) atomicAdd(&cs[b*K_ + kb + i], ca[i]);
    }
}

__global__ void mstepk(float* __restrict__ means_s, float* __restrict__ var_s,
                       float* __restrict__ pi_s,
                       const float* __restrict__ cs, const float* __restrict__ sx,
                       const float* __restrict__ sx2) {
    int idx = blockIdx.x * 256 + threadIdx.x;   // < 8192
    int b = idx >> 10;
    int k = (idx >> 6) & 15;
    int d = idx & 63;
    float csv = cs[b*K_ + k];
    float sum = 0.f;
    #pragma unroll
    for (int j = 0; j < 16; ++j) sum += cs[b*K_ + j];
    float sxv = sx[idx], sx2v = sx2[idx];
    float mean = sxv / (csv + 1e-7f);
    float var  = fmaf(mean*mean, csv, fmaf(-2.0f*mean, sxv, sx2v)) + 1e-6f;
    means_s[idx] = mean;
    var_s[idx]   = var;
    if (d == 0) pi_s[b*K_ + k] = csv / sum;
}

// final lik -> sigmoid(scale*lik + bias) -> out[b][n][k]
__global__ __launch_bounds__(256, 3) void finalk(
        const float* __restrict__ xg,
        const float* __restrict__ pinv, const float* __restrict__ pw,
        const float* __restrict__ pc0,
        const float* __restrict__ scale, const float* __restrict__ bias,
        float* __restrict__ out) {
    __shared__ float pinv_lds[K_*D_];
    __shared__ float pw_lds[K_*D_];
    __shared__ float c0_lds[K_];

    const int t  = threadIdx.x;
    const int b  = blockIdx.y;
    const int n0 = blockIdx.x * TILE;

    for (int i = t; i < K_*D_; i += 256) {
        pinv_lds[i] = pinv[b*K_*D_ + i];
        pw_lds[i]   = pw[b*K_*D_ + i];
    }
    if (t < K_) c0_lds[t] = pc0[b*K_ + t];
    __syncthreads();

    float t1a[16], t2a[16], t1b[16], t2b[16];
    #pragma unroll
    for (int k = 0; k < 16; ++k) { t1a[k]=0.f; t2a[k]=0.f; t1b[k]=0.f; t2b[k]=0.f; }

    const float4* pa = (const float4*)(xg + ((size_t)b*N_ + n0 + t) * D_);
    const float4* pb = pa + 256 * (D_/4);
    const float4* iv4 = (const float4*)pinv_lds;
    const float4* wv4 = (const float4*)pw_lds;

    #pragma unroll 2
    for (int c = 0; c < D_/4; ++c) {
        float4 xa = pa[c], xb = pb[c];
        float4 qa, qb;
        qa.x = xa.x*xa.x; qa.y = xa.y*xa.y; qa.z = xa.z*xa.z; qa.w = xa.w*xa.w;
        qb.x = xb.x*xb.x; qb.y = xb.y*xb.y; qb.z = xb.z*xb.z; qb.w = xb.w*xb.w;
        #pragma unroll
        for (int k = 0; k < 16; ++k) {
            float4 iv = iv4[k*16 + c];
            float4 wv = wv4[k*16 + c];
            t2a[k] = fmaf(qa.x, iv.x, fmaf(qa.y, iv.y, fmaf(qa.z, iv.z, fmaf(qa.w, iv.w, t2a[k]))));
            t1a[k] = fmaf(xa.x, wv.x, fmaf(xa.y, wv.y, fmaf(xa.z, wv.z, fmaf(xa.w, wv.w, t1a[k]))));
            t2b[k] = fmaf(qb.x, iv.x, fmaf(qb.y, iv.y, fmaf(qb.z, iv.z, fmaf(qb.w, iv.w, t2b[k]))));
            t1b[k] = fmaf(xb.x, wv.x, fmaf(xb.y, wv.y, fmaf(xb.z, wv.z, fmaf(xb.w, wv.w, t1b[k]))));
        }
    }

    const float sc = scale[0], bi = bias[0];

    {
        float4* op = (float4*)(out + ((size_t)b*N_ + n0 + t) * (size_t)K_);
        #pragma unroll
        for (int q = 0; q < 4; ++q) {
            float4 o;
            float z0 = (c0_lds[4*q+0] + t1a[4*q+0] - 0.5f*t2a[4*q+0]) * sc + bi;
            float z1 = (c0_lds[4*q+1] + t1a[4*q+1] - 0.5f*t2a[4*q+1]) * sc + bi;
            float z2 = (c0_lds[4*q+2] + t1a[4*q+2] - 0.5f*t2a[4*q+2]) * sc + bi;
            float z3 = (c0_lds[4*q+3] + t1a[4*q+3] - 0.5f*t2a[4*q+3]) * sc + bi;
            o.x = 1.0f / (1.0f + __expf(-z0));
            o.y = 1.0f / (1.0f + __expf(-z1));
            o.z = 1.0f / (1.0f + __expf(-z2));
            o.w = 1.0f / (1.0f + __expf(-z3));
            op[q] = o;
        }
    }
    {
        float4* op = (float4*)(out + ((size_t)b*N_ + n0 + 256 + t) * (size_t)K_);
        #pragma unroll
        for (int q = 0; q < 4; ++q) {
            float4 o;
            float z0 = (c0_lds[4*q+0] + t1b[4*q+0] - 0.5f*t2b[4*q+0]) * sc + bi;
            float z1 = (c0_lds[4*q+1] + t1b[4*q+1] - 0.5f*t2b[4*q+1]) * sc + bi;
            float z2 = (c0_lds[4*q+2] + t1b[4*q+2] - 0.5f*t2b[4*q+2]) * sc + bi;
            float z3 = (c0_lds[4*q+3] + t1b[4*q+3] - 0.5f*t2b[4*q+3]) * sc + bi;
            o.x = 1.0f / (1.0f + __expf(-z0));
            o.y = 1.0f / (1.0f + __expf(-z1));
            o.z = 1.0f / (1.0f + __expf(-z2));
            o.w = 1.0f / (1.0f + __expf(-z3));
            op[q] = o;
        }
    }
}

extern "C" void kernel_launch(void* const* d_in, const int* in_sizes, int n_in,
                              void* d_out, int out_size, void* d_ws, size_t ws_size,
                              hipStream_t stream) {
    const float* xg       = (const float*)d_in[0];
    const float* means_in = (const float*)d_in[1];
    const float* scale    = (const float*)d_in[2];
    const float* bias     = (const float*)d_in[3];
    float* out = (float*)d_out;

    float* ws      = (float*)d_ws;
    float* means_s = ws + 0;
    float* var_s   = ws + 8192;
    float* pi_s    = ws + 16384;
    float* pinv    = ws + 16512;
    float* pw      = ws + 24704;
    float* pc0     = ws + 32896;
    float* cs      = ws + 33024;
    float* sx      = ws + 33152;
    float* sx2     = ws + 41344;

    initk<<<dim3(32), dim3(256), 0, stream>>>(means_in, means_s, var_s, pi_s);

    for (int it = 0; it < 5; ++it) {
        prepk<<<dim3(B_*K_), dim3(64), 0, stream>>>(means_s, var_s, pi_s, pinv, pw, pc0);
        hipMemsetAsync(cs, 0, (size_t)(128 + 8192 + 8192) * sizeof(float), stream);
        estepk<<<dim3(NBLK, B_), dim3(256), 0, stream>>>(xg, pinv, pw, pc0, cs, sx, sx2);
        mstepk<<<dim3(32), dim3(256), 0, stream>>>(means_s, var_s, pi_s, cs, sx, sx2);
    }
    prepk<<<dim3(B_*K_), dim3(64), 0, stream>>>(means_s, var_s, pi_s, pinv, pw, pc0);
    finalk<<<dim3(NBLK, B_), dim3(256), 0, stream>>>(xg, pinv, pw, pc0, scale, bias, out);
}

// Round 2
// 1733.002 us; speedup vs baseline: 1.1121x; 1.1121x over previous
//
#include <hip/hip_runtime.h>
#include <math.h>

#define B_  8
#define T_  400
#define F_  256
#define D_  64
#define K_  16
#define N_  (T_*F_)        // 102400
#define TILE 512
#define NBLK (N_/TILE)     // 200

// ---------------- workspace layout (floats) ----------------
// 0      means_s 8192
// 8192   var_s   8192
// 16384  pi_s    128
// 16512  pinv    8192
// 24704  pw      8192
// 32896  pc0     128
// 33024  cs      128     \
// 33152  sx      8192     > contiguous, zeroed per iteration
// 41344  sx2     8192    /

__global__ void initk(const float* __restrict__ means_in,
                      float* __restrict__ means_s, float* __restrict__ var_s,
                      float* __restrict__ pi_s) {
    int i = blockIdx.x * 256 + threadIdx.x;
    if (i < B_*K_*D_) { means_s[i] = means_in[i]; var_s[i] = 1.0f; }
    if (i < B_*K_)    pi_s[i] = 1.0f / K_;
}

// one wave per (b,k): derived params
__global__ void prepk(const float* __restrict__ means_s, const float* __restrict__ var_s,
                      const float* __restrict__ pi_s,
                      float* __restrict__ pinv, float* __restrict__ pw,
                      float* __restrict__ pc0) {
    int bk = blockIdx.x;          // 0..127
    int d  = threadIdx.x;         // 0..63
    int idx = bk * D_ + d;
    float var = var_s[idx];
    float m   = means_s[idx];
    float inv = 1.0f / (var + 1e-6f);
    pinv[idx] = inv;
    pw[idx]   = m * inv;
    float r1 = logf(6.283185307179586f * var);   // log(2*pi*var)
    float r2 = m * m * inv;
    #pragma unroll
    for (int off = 32; off > 0; off >>= 1) {
        r1 += __shfl_xor(r1, off);
        r2 += __shfl_xor(r2, off);
    }
    if (d == 0) pc0[bk] = logf(pi_s[bk]) - 0.5f * (r1 + r2);
}

// fused E-step: lik -> softmax -> post in LDS -> coalesced accumulate -> atomics
// Params are read with wave-uniform indices -> compiler emits s_load broadcasts.
__global__ __launch_bounds__(256, 4) void estepk(
        const float* __restrict__ xg,
        const float* __restrict__ pinv, const float* __restrict__ pw,
        const float* __restrict__ pc0,
        float* __restrict__ cs, float* __restrict__ sx, float* __restrict__ sx2) {
    __shared__ float post_lds[TILE * 16];     // 32 KB, no pad (2-way conflict is free)

    const int t  = threadIdx.x;
    const int b  = blockIdx.y;
    const int n0 = blockIdx.x * TILE;

    const float4* iv4 = (const float4*)(pinv + (size_t)(b*K_*D_));  // uniform reads
    const float4* wv4 = (const float4*)(pw   + (size_t)(b*K_*D_));

    float c0r[16];
    #pragma unroll
    for (int k = 0; k < 16; ++k) c0r[k] = pc0[b*K_ + k];            // uniform

    // ---- phase A: two points per thread ----
    float t1a[16], t2a[16], t1b[16], t2b[16];
    #pragma unroll
    for (int k = 0; k < 16; ++k) { t1a[k]=0.f; t2a[k]=0.f; t1b[k]=0.f; t2b[k]=0.f; }

    const float4* pa = (const float4*)(xg + ((size_t)b*N_ + n0 + t) * D_);
    const float4* pb = pa + 256 * (D_/4);

    #pragma unroll 2
    for (int c = 0; c < D_/4; ++c) {
        float4 xa = pa[c], xb = pb[c];
        float4 qa, qb;
        qa.x = xa.x*xa.x; qa.y = xa.y*xa.y; qa.z = xa.z*xa.z; qa.w = xa.w*xa.w;
        qb.x = xb.x*xb.x; qb.y = xb.y*xb.y; qb.z = xb.z*xb.z; qb.w = xb.w*xb.w;
        #pragma unroll
        for (int k = 0; k < 16; ++k) {
            float4 iv = iv4[k*16 + c];   // wave-uniform -> SGPR broadcast
            float4 wv = wv4[k*16 + c];
            t2a[k] = fmaf(qa.x, iv.x, fmaf(qa.y, iv.y, fmaf(qa.z, iv.z, fmaf(qa.w, iv.w, t2a[k]))));
            t1a[k] = fmaf(xa.x, wv.x, fmaf(xa.y, wv.y, fmaf(xa.z, wv.z, fmaf(xa.w, wv.w, t1a[k]))));
            t2b[k] = fmaf(qb.x, iv.x, fmaf(qb.y, iv.y, fmaf(qb.z, iv.z, fmaf(qb.w, iv.w, t2b[k]))));
            t1b[k] = fmaf(xb.x, wv.x, fmaf(xb.y, wv.y, fmaf(xb.z, wv.z, fmaf(xb.w, wv.w, t1b[k]))));
        }
    }

    // softmax over K=16 in-thread, post -> LDS
    {
        float lik[16]; float mx = -1e30f;
        #pragma unroll
        for (int k = 0; k < 16; ++k) { lik[k] = c0r[k] + t1a[k] - 0.5f*t2a[k]; mx = fmaxf(mx, lik[k]); }
        float s = 0.f;
        #pragma unroll
        for (int k = 0; k < 16; ++k) { lik[k] = __expf(lik[k] - mx); s += lik[k]; }
        float is = 1.0f / s;
        #pragma unroll
        for (int k = 0; k < 16; ++k) post_lds[t*16 + k] = lik[k] * is;
    }
    {
        float lik[16]; float mx = -1e30f;
        #pragma unroll
        for (int k = 0; k < 16; ++k) { lik[k] = c0r[k] + t1b[k] - 0.5f*t2b[k]; mx = fmaxf(mx, lik[k]); }
        float s = 0.f;
        #pragma unroll
        for (int k = 0; k < 16; ++k) { lik[k] = __expf(lik[k] - mx); s += lik[k]; }
        float is = 1.0f / s;
        #pragma unroll
        for (int k = 0; k < 16; ++k) post_lds[(256 + t)*16 + k] = lik[k] * is;
    }
    __syncthreads();

    // ---- phase B: wave w -> k in [4w,4w+4); lane = (ps<<4)|g ----
    // One dwordx4 per lane covers 4 points x 64 dims, fully coalesced.
    const int lane = t & 63;
    const int kb   = (t >> 6) * 4;
    const int g    = lane & 15;   // d-group: d = 4g..4g+3
    const int ps   = lane >> 4;   // point phase 0..3

    float sa[4][4], s2a[4][4], ca[4];
    #pragma unroll
    for (int i = 0; i < 4; ++i) {
        ca[i] = 0.f;
        #pragma unroll
        for (int j = 0; j < 4; ++j) { sa[i][j] = 0.f; s2a[i][j] = 0.f; }
    }

    const float4* xq = (const float4*)(xg + ((size_t)b*N_ + n0) * D_);

    #pragma unroll 4
    for (int n = 0; n < TILE; n += 4) {
        const int p = n + ps;
        float4 xv = xq[p*16 + g];
        float4 pv = *(const float4*)&post_lds[p*16 + kb];
        float xf[4] = {xv.x, xv.y, xv.z, xv.w};
        float pf[4] = {pv.x, pv.y, pv.z, pv.w};
        float qf[4];
        #pragma unroll
        for (int j = 0; j < 4; ++j) qf[j] = xf[j]*xf[j];
        #pragma unroll
        for (int i = 0; i < 4; ++i) {
            ca[i] += pf[i];
            #pragma unroll
            for (int j = 0; j < 4; ++j) {
                sa[i][j]  = fmaf(pf[i], xf[j], sa[i][j]);
                s2a[i][j] = fmaf(pf[i], qf[j], s2a[i][j]);
            }
        }
    }

    // reduce across the 4 point-phases (xor 16, then xor 32)
    #pragma unroll
    for (int m = 16; m <= 32; m <<= 1) {
        #pragma unroll
        for (int i = 0; i < 4; ++i) {
            ca[i] += __shfl_xor(ca[i], m);
            #pragma unroll
            for (int j = 0; j < 4; ++j) {
                sa[i][j]  += __shfl_xor(sa[i][j],  m);
                s2a[i][j] += __shfl_xor(s2a[i][j], m);
            }
        }
    }

    if (lane < 16) {
        #pragma unroll
        for (int i = 0; i < 4; ++i) {
            #pragma unroll
            for (int j = 0; j < 4; ++j) {
                atomicAdd(&sx [((size_t)(b*K_ + kb + i))*D_ + 4*lane + j], sa[i][j]);
                atomicAdd(&sx2[((size_t)(b*K_ + kb + i))*D_ + 4*lane + j], s2a[i][j]);
            }
        }
        if (lane == 0) {
            #pragma unroll
            for (int i = 0; i < 4; ++i) atomicAdd(&cs[b*K_ + kb + i], ca[i]);
        }
    }
}

__global__ void mstepk(float* __restrict__ means_s, float* __restrict__ var_s,
                       float* __restrict__ pi_s,
                       const float* __restrict__ cs, const float* __restrict__ sx,
                       const float* __restrict__ sx2) {
    int idx = blockIdx.x * 256 + threadIdx.x;   // < 8192
    int b = idx >> 10;
    int k = (idx >> 6) & 15;
    int d = idx & 63;
    float csv = cs[b*K_ + k];
    float sum = 0.f;
    #pragma unroll
    for (int j = 0; j < 16; ++j) sum += cs[b*K_ + j];
    float sxv = sx[idx], sx2v = sx2[idx];
    float mean = sxv / (csv + 1e-7f);
    float var  = fmaf(mean*mean, csv, fmaf(-2.0f*mean, sxv, sx2v)) + 1e-6f;
    means_s[idx] = mean;
    var_s[idx]   = var;
    if (d == 0) pi_s[b*K_ + k] = csv / sum;
}

// final lik -> sigmoid(scale*lik + bias) -> out[b][n][k]
__global__ __launch_bounds__(256, 4) void finalk(
        const float* __restrict__ xg,
        const float* __restrict__ pinv, const float* __restrict__ pw,
        const float* __restrict__ pc0,
        const float* __restrict__ scale, const float* __restrict__ bias,
        float* __restrict__ out) {
    const int t  = threadIdx.x;
    const int b  = blockIdx.y;
    const int n0 = blockIdx.x * TILE;

    const float4* iv4 = (const float4*)(pinv + (size_t)(b*K_*D_));  // uniform
    const float4* wv4 = (const float4*)(pw   + (size_t)(b*K_*D_));

    float c0r[16];
    #pragma unroll
    for (int k = 0; k < 16; ++k) c0r[k] = pc0[b*K_ + k];

    float t1a[16], t2a[16], t1b[16], t2b[16];
    #pragma unroll
    for (int k = 0; k < 16; ++k) { t1a[k]=0.f; t2a[k]=0.f; t1b[k]=0.f; t2b[k]=0.f; }

    const float4* pa = (const float4*)(xg + ((size_t)b*N_ + n0 + t) * D_);
    const float4* pb = pa + 256 * (D_/4);

    #pragma unroll 2
    for (int c = 0; c < D_/4; ++c) {
        float4 xa = pa[c], xb = pb[c];
        float4 qa, qb;
        qa.x = xa.x*xa.x; qa.y = xa.y*xa.y; qa.z = xa.z*xa.z; qa.w = xa.w*xa.w;
        qb.x = xb.x*xb.x; qb.y = xb.y*xb.y; qb.z = xb.z*xb.z; qb.w = xb.w*xb.w;
        #pragma unroll
        for (int k = 0; k < 16; ++k) {
            float4 iv = iv4[k*16 + c];
            float4 wv = wv4[k*16 + c];
            t2a[k] = fmaf(qa.x, iv.x, fmaf(qa.y, iv.y, fmaf(qa.z, iv.z, fmaf(qa.w, iv.w, t2a[k]))));
            t1a[k] = fmaf(xa.x, wv.x, fmaf(xa.y, wv.y, fmaf(xa.z, wv.z, fmaf(xa.w, wv.w, t1a[k]))));
            t2b[k] = fmaf(qb.x, iv.x, fmaf(qb.y, iv.y, fmaf(qb.z, iv.z, fmaf(qb.w, iv.w, t2b[k]))));
            t1b[k] = fmaf(xb.x, wv.x, fmaf(xb.y, wv.y, fmaf(xb.z, wv.z, fmaf(xb.w, wv.w, t1b[k]))));
        }
    }

    const float sc = scale[0], bi = bias[0];

    {
        float4* op = (float4*)(out + ((size_t)b*N_ + n0 + t) * (size_t)K_);
        #pragma unroll
        for (int q = 0; q < 4; ++q) {
            float4 o;
            float z0 = (c0r[4*q+0] + t1a[4*q+0] - 0.5f*t2a[4*q+0]) * sc + bi;
            float z1 = (c0r[4*q+1] + t1a[4*q+1] - 0.5f*t2a[4*q+1]) * sc + bi;
            float z2 = (c0r[4*q+2] + t1a[4*q+2] - 0.5f*t2a[4*q+2]) * sc + bi;
            float z3 = (c0r[4*q+3] + t1a[4*q+3] - 0.5f*t2a[4*q+3]) * sc + bi;
            o.x = 1.0f / (1.0f + __expf(-z0));
            o.y = 1.0f / (1.0f + __expf(-z1));
            o.z = 1.0f / (1.0f + __expf(-z2));
            o.w = 1.0f / (1.0f + __expf(-z3));
            op[q] = o;
        }
    }
    {
        float4* op = (float4*)(out + ((size_t)b*N_ + n0 + 256 + t) * (size_t)K_);
        #pragma unroll
        for (int q = 0; q < 4; ++q) {
            float4 o;
            float z0 = (c0r[4*q+0] + t1b[4*q+0] - 0.5f*t2b[4*q+0]) * sc + bi;
            float z1 = (c0r[4*q+1] + t1b[4*q+1] - 0.5f*t2b[4*q+1]) * sc + bi;
            float z2 = (c0r[4*q+2] + t1b[4*q+2] - 0.5f*t2b[4*q+2]) * sc + bi;
            float z3 = (c0r[4*q+3] + t1b[4*q+3] - 0.5f*t2b[4*q+3]) * sc + bi;
            o.x = 1.0f / (1.0f + __expf(-z0));
            o.y = 1.0f / (1.0f + __expf(-z1));
            o.z = 1.0f / (1.0f + __expf(-z2));
            o.w = 1.0f / (1.0f + __expf(-z3));
            op[q] = o;
        }
    }
}

extern "C" void kernel_launch(void* const* d_in, const int* in_sizes, int n_in,
                              void* d_out, int out_size, void* d_ws, size_t ws_size,
                              hipStream_t stream) {
    const float* xg       = (const float*)d_in[0];
    const float* means_in = (const float*)d_in[1];
    const float* scale    = (const float*)d_in[2];
    const float* bias     = (const float*)d_in[3];
    float* out = (float*)d_out;

    float* ws      = (float*)d_ws;
    float* means_s = ws + 0;
    float* var_s   = ws + 8192;
    float* pi_s    = ws + 16384;
    float* pinv    = ws + 16512;
    float* pw      = ws + 24704;
    float* pc0     = ws + 32896;
    float* cs      = ws + 33024;
    float* sx      = ws + 33152;
    float* sx2     = ws + 41344;

    initk<<<dim3(32), dim3(256), 0, stream>>>(means_in, means_s, var_s, pi_s);

    for (int it = 0; it < 5; ++it) {
        prepk<<<dim3(B_*K_), dim3(64), 0, stream>>>(means_s, var_s, pi_s, pinv, pw, pc0);
        hipMemsetAsync(cs, 0, (size_t)(128 + 8192 + 8192) * sizeof(float), stream);
        estepk<<<dim3(NBLK, B_), dim3(256), 0, stream>>>(xg, pinv, pw, pc0, cs, sx, sx2);
        mstepk<<<dim3(32), dim3(256), 0, stream>>>(means_s, var_s, pi_s, cs, sx, sx2);
    }
    prepk<<<dim3(B_*K_), dim3(64), 0, stream>>>(means_s, var_s, pi_s, pinv, pw, pc0);
    finalk<<<dim3(NBLK, B_), dim3(256), 0, stream>>>(xg, pinv, pw, pc0, scale, bias, out);
}